// Round 1
// baseline (79.535 us; speedup 1.0000x reference)
//
#include <hip/hip_runtime.h>
#include <hip/hip_fp16.h>

#define BATCH 8192
#define IN_F 128
#define OUT_F 256
#define LC 23  // grid_size + order = 23

typedef _Float16 half2v __attribute__((ext_vector_type(2)));

// ---------------------------------------------------------------------------
// dot2 helper: acc += c.lo * w.lo + c.hi * w.hi   (f16 inputs, fp32 accum)
// ---------------------------------------------------------------------------
__device__ __forceinline__ float dot2_acc(unsigned cbits, half2v w,
                                          float w0f, float w1f, float acc) {
#if __has_builtin(__builtin_amdgcn_fdot2)
    union { unsigned u; half2v h; } c;
    c.u = cbits;
    return __builtin_amdgcn_fdot2(c.h, w, acc, false);
#else
    __half2 hc = *reinterpret_cast<const __half2*>(&cbits);
    float2 fc = __half22float2(hc);
    return acc + fc.x * w0f + fc.y * w1f;
#endif
}

// ---------------------------------------------------------------------------
// Kernel A: build f16 gather table
// ctg layout: [j][k][q] -> 16 bytes = 8 x f16:
//   { c[4q+0][j][k], c[4q+0][j][k+1], c[4q+1][j][k], c[4q+1][j][k+1],
//     c[4q+2][j][k], c[4q+2][j][k+1], c[4q+3][j][k], c[4q+3][j][k+1] }
// Total: 128 * 23 * 64 * 16 B = 2.9 MiB (per-XCD-L2 resident)
// ---------------------------------------------------------------------------
__global__ __launch_bounds__(256) void build_ctg_kernel(
    const float* __restrict__ coeffs, unsigned short* __restrict__ ctg) {
    int tid = blockIdx.x * 256 + threadIdx.x;  // over IN_F * LC * 64
    int q = tid & 63;
    int k = (tid >> 6) % LC;
    int j = tid / (64 * LC);
    if (j >= IN_F) return;
    int k1 = (k + 1 < LC) ? (k + 1) : (LC - 1);
    union { unsigned short h[8]; uint4 v; } u;
#pragma unroll
    for (int c = 0; c < 4; ++c) {
        int i = q * 4 + c;
        const float* base = coeffs + ((size_t)i * IN_F + j) * LC;
        u.h[2 * c]     = __half_as_ushort(__float2half(base[k]));
        u.h[2 * c + 1] = __half_as_ushort(__float2half(base[k1]));
    }
    reinterpret_cast<uint4*>(ctg)[tid] = u.v;
}

// ---------------------------------------------------------------------------
// Kernel B: main. One wave per batch row. Lane q owns output cols 4q..4q+3.
// Per j: broadcast x[b][j], compute sigmoid/bin/weights in-wave, one
// coalesced 16B load per lane from ctg, 4x v_dot2_f32_f16.
// ---------------------------------------------------------------------------
__global__ __launch_bounds__(256) void kan_main_kernel(
    const float* __restrict__ x, const unsigned short* __restrict__ ctg,
    float* __restrict__ out) {
    const int wave = threadIdx.x >> 6;
    const int lane = threadIdx.x & 63;
    const int b = blockIdx.x * 4 + wave;

    const float4* xrow4 = reinterpret_cast<const float4*>(x + (size_t)b * IN_F);
    const char* ctg_lane = reinterpret_cast<const char*>(ctg) + lane * 16;

    float acc0 = 0.f, acc1 = 0.f, acc2 = 0.f, acc3 = 0.f;

#pragma unroll 2
    for (int j4 = 0; j4 < IN_F / 4; ++j4) {
        float4 xv = xrow4[j4];  // broadcast (wave-uniform) 16B load
#pragma unroll
        for (int u = 0; u < 4; ++u) {
            float xs = (u == 0) ? xv.x : (u == 1) ? xv.y : (u == 2) ? xv.z : xv.w;
            int j = j4 * 4 + u;
            // sigmoid -> fractional bin
            float s = 1.0f / (1.0f + __expf(-xs));
            float idxf = s * 19.0f;
            int k = (int)idxf;           // floor (idxf >= 0)
            k = (k > 18) ? 18 : k;       // safety clamp (matches ref semantics)
            float w1 = idxf - (float)k;
            float w0 = 1.0f - w1;
            half2v w;
            w[0] = (_Float16)w0;
            w[1] = (_Float16)w1;
            // coalesced gather: 64 lanes * 16B = 1KB contiguous at (j,k)
            const uint4 e = *reinterpret_cast<const uint4*>(
                ctg_lane + (size_t)(j * LC + k) * 1024);
            acc0 = dot2_acc(e.x, w, w0, w1, acc0);
            acc1 = dot2_acc(e.y, w, w0, w1, acc1);
            acc2 = dot2_acc(e.z, w, w0, w1, acc2);
            acc3 = dot2_acc(e.w, w, w0, w1, acc3);
        }
    }
    float4 r = make_float4(acc0, acc1, acc2, acc3);
    reinterpret_cast<float4*>(out + (size_t)b * OUT_F)[lane] = r;
}

// ---------------------------------------------------------------------------
// Fallback (only if d_ws is too small): gather fp32 coeffs directly.
// Slow but correct.
// ---------------------------------------------------------------------------
__global__ __launch_bounds__(256) void kan_direct_kernel(
    const float* __restrict__ x, const float* __restrict__ coeffs,
    float* __restrict__ out) {
    const int wave = threadIdx.x >> 6;
    const int lane = threadIdx.x & 63;
    const int b = blockIdx.x * 4 + wave;
    const float* xrow = x + (size_t)b * IN_F;
    float acc[4] = {0.f, 0.f, 0.f, 0.f};
    for (int j = 0; j < IN_F; ++j) {
        float xs = xrow[j];
        float s = 1.0f / (1.0f + __expf(-xs));
        float idxf = s * 19.0f;
        int k = (int)idxf;
        k = (k > 18) ? 18 : k;
        float w1 = idxf - (float)k;
        float w0 = 1.0f - w1;
#pragma unroll
        for (int c = 0; c < 4; ++c) {
            int i = lane * 4 + c;
            const float* cb = coeffs + ((size_t)i * IN_F + j) * LC + k;
            acc[c] += w0 * cb[0] + w1 * cb[1];
        }
    }
    float4 r = make_float4(acc[0], acc[1], acc[2], acc[3]);
    reinterpret_cast<float4*>(out + (size_t)b * OUT_F)[lane] = r;
}

// ---------------------------------------------------------------------------
extern "C" void kernel_launch(void* const* d_in, const int* in_sizes, int n_in,
                              void* d_out, int out_size, void* d_ws,
                              size_t ws_size, hipStream_t stream) {
    const float* x = (const float*)d_in[0];       // [8192, 128] fp32
    const float* coeffs = (const float*)d_in[1];  // [256, 128, 23] fp32
    float* out = (float*)d_out;                   // [8192, 256] fp32

    const size_t ctg_bytes = (size_t)IN_F * LC * 64 * 16;  // ~2.9 MiB

    if (d_ws != nullptr && ws_size >= ctg_bytes) {
        unsigned short* ctg = (unsigned short*)d_ws;
        const int totalA = IN_F * LC * 64;  // 188416 = 736 * 256
        build_ctg_kernel<<<(totalA + 255) / 256, 256, 0, stream>>>(coeffs, ctg);
        kan_main_kernel<<<BATCH / 4, 256, 0, stream>>>(x, ctg, out);
    } else {
        kan_direct_kernel<<<BATCH / 4, 256, 0, stream>>>(x, coeffs, out);
    }
}

// Round 2
// 49.342 us; speedup vs baseline: 1.6119x; 1.6119x over previous
//
#include <hip/hip_runtime.h>
#include <hip/hip_fp16.h>

#define BATCH 8192
#define IN_F 128
#define OUT_F 256
#define LC 23  // grid_size + order = 23

typedef _Float16 half2v __attribute__((ext_vector_type(2)));

// ---------------------------------------------------------------------------
// dot2: acc += c.lo*w.lo + c.hi*w.hi  (f16 inputs, fp32 accumulate)
// ---------------------------------------------------------------------------
__device__ __forceinline__ float dot2_acc(unsigned cbits, unsigned wbits,
                                          float acc) {
#if __has_builtin(__builtin_amdgcn_fdot2)
    union { unsigned u; half2v h; } c, w;
    c.u = cbits;
    w.u = wbits;
    return __builtin_amdgcn_fdot2(c.h, w.h, acc, false);
#else
    __half2 hc = *reinterpret_cast<const __half2*>(&cbits);
    __half2 hw = *reinterpret_cast<const __half2*>(&wbits);
    float2 fc = __half22float2(hc);
    float2 fw = __half22float2(hw);
    return acc + fc.x * fw.x + fc.y * fw.y;
#endif
}

// ---------------------------------------------------------------------------
// Kernel A: build f16 gather table (unchanged from R1 — ~2.9 MiB, L2-resident)
// ctg layout: [j][k][q] -> 16 B = 8 x f16:
//   { c[4q+0][j][k], c[4q+0][j][k+1], ..., c[4q+3][j][k], c[4q+3][j][k+1] }
// ---------------------------------------------------------------------------
__global__ __launch_bounds__(256) void build_ctg_kernel(
    const float* __restrict__ coeffs, unsigned short* __restrict__ ctg) {
    int tid = blockIdx.x * 256 + threadIdx.x;  // over IN_F * LC * 64
    int q = tid & 63;
    int k = (tid >> 6) % LC;
    int j = tid / (64 * LC);
    if (j >= IN_F) return;
    int k1 = (k + 1 < LC) ? (k + 1) : (LC - 1);
    union { unsigned short h[8]; uint4 v; } u;
#pragma unroll
    for (int c = 0; c < 4; ++c) {
        int i = q * 4 + c;
        const float* base = coeffs + ((size_t)i * IN_F + j) * LC;
        u.h[2 * c]     = __half_as_ushort(__float2half(base[k]));
        u.h[2 * c + 1] = __half_as_ushort(__float2half(base[k1]));
    }
    reinterpret_cast<uint4*>(ctg)[tid] = u.v;
}

// ---------------------------------------------------------------------------
// Kernel B: main. One wave per batch row; lane q owns output cols 4q..4q+3.
// Phase 1 (per row, once): each lane computes metadata for 2 j's
//   {byte offset into ctg (u32), packed half2 (w0,w1)} -> 1 KB/wave in LDS.
// Phase 2 (inner loop): per 2 j's: one wave-uniform ds_read_b128 (broadcast),
//   per j: v_add_u32 address + global_load_dwordx4 + 4x v_dot2_f32_f16.
// ---------------------------------------------------------------------------
__global__ __launch_bounds__(256) void kan_main_kernel(
    const float* __restrict__ x, const char* __restrict__ ctg,
    float* __restrict__ out) {
    __shared__ unsigned meta[4][2 * IN_F];  // per wave: 128 j x {off, wbits}

    const int wave = threadIdx.x >> 6;
    const int lane = threadIdx.x & 63;
    const int b = blockIdx.x * 4 + wave;

    // ---- Phase 1: metadata for j = 2*lane, 2*lane+1 ----
    float2 xv = reinterpret_cast<const float2*>(x + (size_t)b * IN_F)[lane];
    uint4 m;
#pragma unroll
    for (int t = 0; t < 2; ++t) {
        float xs = t ? xv.y : xv.x;
        float s = 1.0f / (1.0f + __expf(-xs));
        float idxf = s * 19.0f;
        int k = (int)idxf;            // floor (idxf >= 0)
        k = (k > 18) ? 18 : k;        // s==1.0 edge: w1 becomes exactly 1.0
        float w1 = idxf - (float)k;
        float w0 = 1.0f - w1;
        int j = 2 * lane + t;
        unsigned off = (unsigned)((j * LC + k) << 10);  // *1024 B per (j,k) row
        half2v w;
        w[0] = (_Float16)w0;
        w[1] = (_Float16)w1;
        unsigned wbits = *reinterpret_cast<unsigned*>(&w);
        if (t == 0) { m.x = off; m.y = wbits; }
        else        { m.z = off; m.w = wbits; }
    }
    reinterpret_cast<uint4*>(&meta[wave][0])[lane] = m;
    __syncthreads();

    // ---- Phase 2: gather + dot ----
    const unsigned lanebase = lane * 16;
    const uint4* mrow = reinterpret_cast<const uint4*>(&meta[wave][0]);
    float acc0 = 0.f, acc1 = 0.f, acc2 = 0.f, acc3 = 0.f;

#pragma unroll 8
    for (int j2 = 0; j2 < IN_F / 2; ++j2) {
        uint4 mm = mrow[j2];  // wave-uniform LDS read (broadcast): meta j, j+1
        {
            const uint4 e = *reinterpret_cast<const uint4*>(
                ctg + (size_t)(lanebase + mm.x));
            acc0 = dot2_acc(e.x, mm.y, acc0);
            acc1 = dot2_acc(e.y, mm.y, acc1);
            acc2 = dot2_acc(e.z, mm.y, acc2);
            acc3 = dot2_acc(e.w, mm.y, acc3);
        }
        {
            const uint4 e = *reinterpret_cast<const uint4*>(
                ctg + (size_t)(lanebase + mm.z));
            acc0 = dot2_acc(e.x, mm.w, acc0);
            acc1 = dot2_acc(e.y, mm.w, acc1);
            acc2 = dot2_acc(e.z, mm.w, acc2);
            acc3 = dot2_acc(e.w, mm.w, acc3);
        }
    }
    float4 r = make_float4(acc0, acc1, acc2, acc3);
    reinterpret_cast<float4*>(out + (size_t)b * OUT_F)[lane] = r;
}

// ---------------------------------------------------------------------------
// Fallback (only if d_ws too small): gather fp32 coeffs directly.
// ---------------------------------------------------------------------------
__global__ __launch_bounds__(256) void kan_direct_kernel(
    const float* __restrict__ x, const float* __restrict__ coeffs,
    float* __restrict__ out) {
    const int wave = threadIdx.x >> 6;
    const int lane = threadIdx.x & 63;
    const int b = blockIdx.x * 4 + wave;
    const float* xrow = x + (size_t)b * IN_F;
    float acc[4] = {0.f, 0.f, 0.f, 0.f};
    for (int j = 0; j < IN_F; ++j) {
        float xs = xrow[j];
        float s = 1.0f / (1.0f + __expf(-xs));
        float idxf = s * 19.0f;
        int k = (int)idxf;
        k = (k > 18) ? 18 : k;
        float w1 = idxf - (float)k;
        float w0 = 1.0f - w1;
#pragma unroll
        for (int c = 0; c < 4; ++c) {
            int i = lane * 4 + c;
            const float* cb = coeffs + ((size_t)i * IN_F + j) * LC + k;
            acc[c] += w0 * cb[0] + w1 * cb[1];
        }
    }
    float4 r = make_float4(acc[0], acc[1], acc[2], acc[3]);
    reinterpret_cast<float4*>(out + (size_t)b * OUT_F)[lane] = r;
}

// ---------------------------------------------------------------------------
extern "C" void kernel_launch(void* const* d_in, const int* in_sizes, int n_in,
                              void* d_out, int out_size, void* d_ws,
                              size_t ws_size, hipStream_t stream) {
    const float* x = (const float*)d_in[0];       // [8192, 128] fp32
    const float* coeffs = (const float*)d_in[1];  // [256, 128, 23] fp32
    float* out = (float*)d_out;                   // [8192, 256] fp32

    const size_t ctg_bytes = (size_t)IN_F * LC * 64 * 16;  // ~2.9 MiB

    if (d_ws != nullptr && ws_size >= ctg_bytes) {
        char* ctg = (char*)d_ws;
        const int totalA = IN_F * LC * 64;  // 188416 = 736 * 256
        build_ctg_kernel<<<(totalA + 255) / 256, 256, 0, stream>>>(
            coeffs, (unsigned short*)ctg);
        kan_main_kernel<<<BATCH / 4, 256, 0, stream>>>(x, ctg, out);
    } else {
        kan_direct_kernel<<<BATCH / 4, 256, 0, stream>>>(x, coeffs, out);
    }
}